// Round 4
// baseline (343.103 us; speedup 1.0000x reference)
//
#include <hip/hip_runtime.h>
#include <hip/hip_bf16.h>

#define HIDDEN 128
#define NB 64
#define TG 2048             // table cells (2 MB table -> L2-resident per XCD)
#define TPTS (TG + 1)       // table points
#define TMAX 32.0f
#define TINV ((float)TG / TMAX)   // 64 cells per unit of squared distance
#define VPAD 53248          // 13 * 4096, >= V+1, multiple of 4096 for the scan
#define NTBLK ((TPTS + 1) / 2)    // 1025 table blocks (2 grid points each)
#define GNODES 32           // nodes per gather_mlp block (8 per wave)

typedef float f2v __attribute__((ext_vector_type(2)));

// ---------------------------------------------------------------------------
// K1: fused weight-transpose (blocks 0..63) + dest histogram (blocks 64..).
// ---------------------------------------------------------------------------
__global__ __launch_bounds__(256) void prep_hist(
    const float* __restrict__ W1, const float* __restrict__ W2,
    float* __restrict__ W1T, float* __restrict__ W2T,
    const int* __restrict__ dest, int* __restrict__ cnt, int E) {
    const int b = blockIdx.x;
    if (b < 64) {
        const int i = b * 256 + threadIdx.x;        // 0..16383
        if (i < NB * HIDDEN) {
            const int r = i >> 7, c = i & 127;
            W1T[c * NB + r] = W1[i];
        }
        if (i < HIDDEN * HIDDEN) {
            const int k = i >> 7, c = i & 127;
            W2T[c * HIDDEN + k] = W2[i];
        }
    } else {
        const int e = (b - 64) * 256 + threadIdx.x;
        if (e < E) atomicAdd(&cnt[dest[e]], 1);
    }
}

// ---------------------------------------------------------------------------
// K2: exclusive scan over VPAD counts (single block, 1024 threads).
// ---------------------------------------------------------------------------
__global__ __launch_bounds__(1024) void scan_counts(const int* __restrict__ cnt,
                                                    int* __restrict__ starts,
                                                    int* __restrict__ cursor) {
    __shared__ int wsum[16];
    __shared__ int chunk_carry;
    const int tid = threadIdx.x;
    const int lane = tid & 63;
    const int wv = tid >> 6;
    if (tid == 0) chunk_carry = 0;
    __syncthreads();
    for (int base = 0; base < VPAD; base += 4096) {
        const int i0 = base + tid * 4;
        const int4 c = *(const int4*)(cnt + i0);
        const int s1 = c.x + c.y;
        const int s2 = s1 + c.z;
        const int s3 = s2 + c.w;
        int s = s3;
#pragma unroll
        for (int d = 1; d < 64; d <<= 1) {
            const int n = __shfl_up(s, d);
            if (lane >= d) s += n;
        }
        if (lane == 63) wsum[wv] = s;
        __syncthreads();
        int woff = 0;
#pragma unroll
        for (int w = 0; w < 16; ++w)
            if (w < wv) woff += wsum[w];
        const int excl = chunk_carry + woff + (s - s3);
        int4 o;
        o.x = excl;
        o.y = excl + c.x;
        o.z = excl + s1;
        o.w = excl + s2;
        *(int4*)(starts + i0) = o;
        *(int4*)(cursor + i0) = o;
        __syncthreads();
        if (tid == 0) {
            int tot = 0;
#pragma unroll
            for (int w = 0; w < 16; ++w) tot += wsum[w];
            chunk_carry += tot;
        }
        __syncthreads();
    }
}

// ---------------------------------------------------------------------------
// K3: fused table build (blocks 0..NTBLK-1, 2 grid points per block) +
// CSR edge scatter (blocks NTBLK..). Independent work.
// Table layout: interleaved pairs Tp[g][c] = {T[g][c], T[g+1][c]}.
// ---------------------------------------------------------------------------
__global__ __launch_bounds__(256) void table_scatter(
    const float* __restrict__ W1T, const float* __restrict__ W2T,
    float2* __restrict__ Tp,
    const int* __restrict__ src, const int* __restrict__ dest,
    const float* __restrict__ R, int* __restrict__ cursor,
    float2* __restrict__ ep, int E) {
    const int b = blockIdx.x;
    if (b < NTBLK) {
        __shared__ float rbf[2][NB];
        __shared__ float m1[2][HIDDEN];
        const int half = threadIdx.x >> 7;   // 0 or 1
        const int c = threadIdx.x & 127;
        const int g = b * 2 + half;          // grid point (may exceed TG once)
        const float d = (float)g * (TMAX / (float)TG);
        if (c < NB) {
            const float center = 25.0f * (float)c / 63.0f;
            const float w = 25.0f / 63.0f;
            const float z = d - center;
            rbf[half][c] = expf(-(z * z) / (2.0f * w * w));
        }
        __syncthreads();
        const float4* w1 = (const float4*)(W1T + c * NB);
        float acc = 0.0f;
#pragma unroll
        for (int b4 = 0; b4 < NB / 4; ++b4) {
            const float4 w = w1[b4];
            acc = fmaf(rbf[half][4 * b4 + 0], w.x, acc);
            acc = fmaf(rbf[half][4 * b4 + 1], w.y, acc);
            acc = fmaf(rbf[half][4 * b4 + 2], w.z, acc);
            acc = fmaf(rbf[half][4 * b4 + 3], w.w, acc);
        }
        m1[half][c] = fmaxf(acc, 0.0f);
        __syncthreads();
        const float4* w2 = (const float4*)(W2T + c * HIDDEN);
        float acc2 = 0.0f;
#pragma unroll 8
        for (int k4 = 0; k4 < HIDDEN / 4; ++k4) {
            const float4 w = w2[k4];
            acc2 = fmaf(m1[half][4 * k4 + 0], w.x, acc2);
            acc2 = fmaf(m1[half][4 * k4 + 1], w.y, acc2);
            acc2 = fmaf(m1[half][4 * k4 + 2], w.z, acc2);
            acc2 = fmaf(m1[half][4 * k4 + 3], w.w, acc2);
        }
        const float v = fmaxf(acc2, 0.0f);
        if (g < TG) Tp[(size_t)g * HIDDEN + c].x = v;        // point g of cell g
        if (g >= 1 && g <= TG) Tp[(size_t)(g - 1) * HIDDEN + c].y = v;
    } else {
        const int e = (b - NTBLK) * 256 + threadIdx.x;
        if (e >= E) return;
        const int s = src[e];
        const int d = dest[e];
        const float dx = R[3 * s + 0] - R[3 * d + 0];
        const float dy = R[3 * s + 1] - R[3 * d + 1];
        const float dz = R[3 * s + 2] - R[3 * d + 2];
        const float D2 = fmaf(dx, dx, fmaf(dy, dy, dz * dz));
        const float u = fminf(D2 * TINV, (float)TG);
        const int pos = atomicAdd(&cursor[d], 1);
        ep[pos] = make_float2(__int_as_float(s), u);
    }
}

// ---------------------------------------------------------------------------
// K4: fused gather + node MLP. Block = 256 threads = 4 waves; each wave owns
// 8 consecutive nodes: gathers their H rows into its own LDS rows, then runs
// the 2-layer MLP on them (register-blocked). No __syncthreads needed — each
// wave only ever touches its own 8 LDS rows. ts aliases hs (reads complete
// before overwrite, per-wave program order).
// ---------------------------------------------------------------------------
__global__ __launch_bounds__(256) void gather_mlp(
    const int* __restrict__ starts, const float2* __restrict__ ep,
    const float2* __restrict__ X2, const float4* __restrict__ Tp4,
    const float* __restrict__ U1, const float* __restrict__ b1,
    const float* __restrict__ U2, const float* __restrict__ b2,
    float* __restrict__ out, int V) {
    __shared__ float hs[GNODES * HIDDEN];   // 16 KB
    const int tid = threadIdx.x;
    const int lane = tid & 63;
    const int wave = tid >> 6;
    const int nbase = blockIdx.x * GNODES + wave * 8;

    // ---- gather phase: 8 nodes per wave, 2-edge unroll, nt loads on streams
    for (int j = 0; j < 8; ++j) {
        const int node = nbase + j;
        float accx = 0.0f, accy = 0.0f;
        if (node < V) {
            int i = starts[node];
            const int end = starts[node + 1];
            for (; i + 2 <= end; i += 2) {
                const f2v e0 = __builtin_nontemporal_load((const f2v*)(ep + i));
                const f2v e1 = __builtin_nontemporal_load((const f2v*)(ep + i + 1));
                const int s0 = __float_as_int(e0.x);
                const int s1 = __float_as_int(e1.x);
                int g0 = (int)e0.y; if (g0 > TG - 1) g0 = TG - 1;
                int g1 = (int)e1.y; if (g1 > TG - 1) g1 = TG - 1;
                const float t0 = e0.y - (float)g0;
                const float t1 = e1.y - (float)g1;
                const float4 q0 = Tp4[(size_t)g0 * 64 + lane];
                const float4 q1 = Tp4[(size_t)g1 * 64 + lane];
                const f2v x0 = __builtin_nontemporal_load((const f2v*)(X2 + (size_t)s0 * 64 + lane));
                const f2v x1 = __builtin_nontemporal_load((const f2v*)(X2 + (size_t)s1 * 64 + lane));
                accx = fmaf(fmaf(t0, q0.y - q0.x, q0.x), x0.x, accx);
                accy = fmaf(fmaf(t0, q0.w - q0.z, q0.z), x0.y, accy);
                accx = fmaf(fmaf(t1, q1.y - q1.x, q1.x), x1.x, accx);
                accy = fmaf(fmaf(t1, q1.w - q1.z, q1.z), x1.y, accy);
            }
            if (i < end) {
                const f2v e0 = __builtin_nontemporal_load((const f2v*)(ep + i));
                const int s0 = __float_as_int(e0.x);
                int g0 = (int)e0.y; if (g0 > TG - 1) g0 = TG - 1;
                const float t0 = e0.y - (float)g0;
                const float4 q0 = Tp4[(size_t)g0 * 64 + lane];
                const f2v x0 = __builtin_nontemporal_load((const f2v*)(X2 + (size_t)s0 * 64 + lane));
                accx = fmaf(fmaf(t0, q0.y - q0.x, q0.x), x0.x, accx);
                accy = fmaf(fmaf(t0, q0.w - q0.z, q0.z), x0.y, accy);
            }
        }
        *(float2*)&hs[(wave * 8 + j) * HIDDEN + 2 * lane] = make_float2(accx, accy);
    }

    // ---- MLP phase (per-wave, register-blocked 8 rows x 2 cols)
    const float2* U1g = (const float2*)U1;
    const float2* U2g = (const float2*)U2;
    const float2 bb1 = ((const float2*)b1)[lane];
    const float2 bb2 = ((const float2*)b2)[lane];
    const int lr0 = wave * 8;

    float2 acc[8];
#pragma unroll
    for (int j = 0; j < 8; ++j) acc[j] = bb1;
    for (int k4 = 0; k4 < HIDDEN / 4; ++k4) {
        const float2 u0 = U1g[(k4 * 4 + 0) * 64 + lane];
        const float2 u1 = U1g[(k4 * 4 + 1) * 64 + lane];
        const float2 u2 = U1g[(k4 * 4 + 2) * 64 + lane];
        const float2 u3 = U1g[(k4 * 4 + 3) * 64 + lane];
#pragma unroll
        for (int j = 0; j < 8; ++j) {
            const float4 h4 = *(const float4*)&hs[(lr0 + j) * HIDDEN + k4 * 4];
            acc[j].x = fmaf(h4.x, u0.x, acc[j].x);
            acc[j].y = fmaf(h4.x, u0.y, acc[j].y);
            acc[j].x = fmaf(h4.y, u1.x, acc[j].x);
            acc[j].y = fmaf(h4.y, u1.y, acc[j].y);
            acc[j].x = fmaf(h4.z, u2.x, acc[j].x);
            acc[j].y = fmaf(h4.z, u2.y, acc[j].y);
            acc[j].x = fmaf(h4.w, u3.x, acc[j].x);
            acc[j].y = fmaf(h4.w, u3.y, acc[j].y);
        }
    }
#pragma unroll
    for (int j = 0; j < 8; ++j) {
        float2 t;
        t.x = fmaxf(acc[j].x, 0.0f);
        t.y = fmaxf(acc[j].y, 0.0f);
        *(float2*)&hs[(lr0 + j) * HIDDEN + 2 * lane] = t;   // alias: safe per-wave
    }

#pragma unroll
    for (int j = 0; j < 8; ++j) acc[j] = bb2;
    for (int k4 = 0; k4 < HIDDEN / 4; ++k4) {
        const float2 u0 = U2g[(k4 * 4 + 0) * 64 + lane];
        const float2 u1 = U2g[(k4 * 4 + 1) * 64 + lane];
        const float2 u2 = U2g[(k4 * 4 + 2) * 64 + lane];
        const float2 u3 = U2g[(k4 * 4 + 3) * 64 + lane];
#pragma unroll
        for (int j = 0; j < 8; ++j) {
            const float4 h4 = *(const float4*)&hs[(lr0 + j) * HIDDEN + k4 * 4];
            acc[j].x = fmaf(h4.x, u0.x, acc[j].x);
            acc[j].y = fmaf(h4.x, u0.y, acc[j].y);
            acc[j].x = fmaf(h4.y, u1.x, acc[j].x);
            acc[j].y = fmaf(h4.y, u1.y, acc[j].y);
            acc[j].x = fmaf(h4.z, u2.x, acc[j].x);
            acc[j].y = fmaf(h4.z, u2.y, acc[j].y);
            acc[j].x = fmaf(h4.w, u3.x, acc[j].x);
            acc[j].y = fmaf(h4.w, u3.y, acc[j].y);
        }
    }
    float2* out2 = (float2*)out;
#pragma unroll
    for (int j = 0; j < 8; ++j) {
        const int row = nbase + j;
        if (row < V) out2[(size_t)row * 64 + lane] = acc[j];
    }
}

// ---------------------------------------------------------------------------
extern "C" void kernel_launch(void* const* d_in, const int* in_sizes, int n_in,
                              void* d_out, int out_size, void* d_ws, size_t ws_size,
                              hipStream_t stream) {
    const float* X = (const float*)d_in[0];
    const float* R = (const float*)d_in[1];
    const int* src = (const int*)d_in[2];
    const int* dest = (const int*)d_in[3];
    const float* W1 = (const float*)d_in[4];
    const float* W2 = (const float*)d_in[5];
    const float* U1 = (const float*)d_in[6];
    const float* b1 = (const float*)d_in[7];
    const float* U2 = (const float*)d_in[8];
    const float* b2 = (const float*)d_in[9];

    const int V = in_sizes[0] / HIDDEN;
    const int E = in_sizes[2];
    const int EB = (E + 255) / 256;

    // workspace layout (16B-aligned sections)
    char* base = (char*)d_ws;
    float2* Tp = (float2*)base;                 base += (size_t)TG * HIDDEN * sizeof(float2);
    float2* ep = (float2*)base;                 base += (size_t)E * sizeof(float2);
    int* cnt = (int*)base;                      base += (size_t)VPAD * sizeof(int);
    int* starts = (int*)base;                   base += (size_t)VPAD * sizeof(int);
    int* cursor = (int*)base;                   base += (size_t)VPAD * sizeof(int);
    float* W1T = (float*)base;                  base += (size_t)NB * HIDDEN * sizeof(float);
    float* W2T = (float*)base;

    hipMemsetAsync(cnt, 0, (size_t)VPAD * sizeof(int), stream);
    prep_hist<<<64 + EB, 256, 0, stream>>>(W1, W2, W1T, W2T, dest, cnt, E);
    scan_counts<<<1, 1024, 0, stream>>>(cnt, starts, cursor);
    table_scatter<<<NTBLK + EB, 256, 0, stream>>>(W1T, W2T, Tp, src, dest, R,
                                                  cursor, ep, E);
    gather_mlp<<<(V + GNODES - 1) / GNODES, 256, 0, stream>>>(
        starts, ep, (const float2*)X, (const float4*)Tp, U1, b1, U2, b2,
        (float*)d_out, V);
}

// Round 5
// 265.496 us; speedup vs baseline: 1.2923x; 1.2923x over previous
//
#include <hip/hip_runtime.h>
#include <hip/hip_bf16.h>

#define HIDDEN 128
#define NB 64
#define TG 2048             // table cells (2 MB table -> L2-resident per XCD)
#define TPTS (TG + 1)       // table points
#define TMAX 32.0f
#define TINV ((float)TG / TMAX)   // 64 cells per unit of squared distance
#define VPAD 53248          // 13 * 4096, >= V+1, multiple of 4096 for the scan
#define NTBLK ((TPTS + 1) / 2)    // 1025 table blocks (2 grid points each)

typedef float f2v __attribute__((ext_vector_type(2)));

// ---------------------------------------------------------------------------
// K1: fused weight-transpose (blocks 0..63) + dest histogram (blocks 64..).
// ---------------------------------------------------------------------------
__global__ __launch_bounds__(256) void prep_hist(
    const float* __restrict__ W1, const float* __restrict__ W2,
    float* __restrict__ W1T, float* __restrict__ W2T,
    const int* __restrict__ dest, int* __restrict__ cnt, int E) {
    const int b = blockIdx.x;
    if (b < 64) {
        const int i = b * 256 + threadIdx.x;        // 0..16383
        if (i < NB * HIDDEN) {
            const int r = i >> 7, c = i & 127;
            W1T[c * NB + r] = W1[i];
        }
        if (i < HIDDEN * HIDDEN) {
            const int k = i >> 7, c = i & 127;
            W2T[c * HIDDEN + k] = W2[i];
        }
    } else {
        const int e = (b - 64) * 256 + threadIdx.x;
        if (e < E) atomicAdd(&cnt[dest[e]], 1);
    }
}

// ---------------------------------------------------------------------------
// K2: exclusive scan over VPAD counts (single block, 1024 threads).
// ---------------------------------------------------------------------------
__global__ __launch_bounds__(1024) void scan_counts(const int* __restrict__ cnt,
                                                    int* __restrict__ starts,
                                                    int* __restrict__ cursor) {
    __shared__ int wsum[16];
    __shared__ int chunk_carry;
    const int tid = threadIdx.x;
    const int lane = tid & 63;
    const int wv = tid >> 6;
    if (tid == 0) chunk_carry = 0;
    __syncthreads();
    for (int base = 0; base < VPAD; base += 4096) {
        const int i0 = base + tid * 4;
        const int4 c = *(const int4*)(cnt + i0);
        const int s1 = c.x + c.y;
        const int s2 = s1 + c.z;
        const int s3 = s2 + c.w;
        int s = s3;
#pragma unroll
        for (int d = 1; d < 64; d <<= 1) {
            const int n = __shfl_up(s, d);
            if (lane >= d) s += n;
        }
        if (lane == 63) wsum[wv] = s;
        __syncthreads();
        int woff = 0;
#pragma unroll
        for (int w = 0; w < 16; ++w)
            if (w < wv) woff += wsum[w];
        const int excl = chunk_carry + woff + (s - s3);
        int4 o;
        o.x = excl;
        o.y = excl + c.x;
        o.z = excl + s1;
        o.w = excl + s2;
        *(int4*)(starts + i0) = o;
        *(int4*)(cursor + i0) = o;
        __syncthreads();
        if (tid == 0) {
            int tot = 0;
#pragma unroll
            for (int w = 0; w < 16; ++w) tot += wsum[w];
            chunk_carry += tot;
        }
        __syncthreads();
    }
}

// ---------------------------------------------------------------------------
// K3: fused table build (blocks 0..NTBLK-1, 2 grid points per block) +
// CSR edge scatter (blocks NTBLK..). Independent work.
// Table layout: interleaved pairs Tp[g][c] = {T[g][c], T[g+1][c]}.
// ---------------------------------------------------------------------------
__global__ __launch_bounds__(256) void table_scatter(
    const float* __restrict__ W1T, const float* __restrict__ W2T,
    float2* __restrict__ Tp,
    const int* __restrict__ src, const int* __restrict__ dest,
    const float* __restrict__ R, int* __restrict__ cursor,
    float2* __restrict__ ep, int E) {
    const int b = blockIdx.x;
    if (b < NTBLK) {
        __shared__ float rbf[2][NB];
        __shared__ float m1[2][HIDDEN];
        const int half = threadIdx.x >> 7;   // 0 or 1
        const int c = threadIdx.x & 127;
        const int g = b * 2 + half;          // grid point
        const float d = (float)g * (TMAX / (float)TG);
        if (c < NB) {
            const float center = 25.0f * (float)c / 63.0f;
            const float w = 25.0f / 63.0f;
            const float z = d - center;
            rbf[half][c] = expf(-(z * z) / (2.0f * w * w));
        }
        __syncthreads();
        const float4* w1 = (const float4*)(W1T + c * NB);
        float acc = 0.0f;
#pragma unroll
        for (int b4 = 0; b4 < NB / 4; ++b4) {
            const float4 w = w1[b4];
            acc = fmaf(rbf[half][4 * b4 + 0], w.x, acc);
            acc = fmaf(rbf[half][4 * b4 + 1], w.y, acc);
            acc = fmaf(rbf[half][4 * b4 + 2], w.z, acc);
            acc = fmaf(rbf[half][4 * b4 + 3], w.w, acc);
        }
        m1[half][c] = fmaxf(acc, 0.0f);
        __syncthreads();
        const float4* w2 = (const float4*)(W2T + c * HIDDEN);
        float acc2 = 0.0f;
#pragma unroll 8
        for (int k4 = 0; k4 < HIDDEN / 4; ++k4) {
            const float4 w = w2[k4];
            acc2 = fmaf(m1[half][4 * k4 + 0], w.x, acc2);
            acc2 = fmaf(m1[half][4 * k4 + 1], w.y, acc2);
            acc2 = fmaf(m1[half][4 * k4 + 2], w.z, acc2);
            acc2 = fmaf(m1[half][4 * k4 + 3], w.w, acc2);
        }
        const float v = fmaxf(acc2, 0.0f);
        if (g < TG) Tp[(size_t)g * HIDDEN + c].x = v;        // point g of cell g
        if (g >= 1 && g <= TG) Tp[(size_t)(g - 1) * HIDDEN + c].y = v;
    } else {
        const int e = (b - NTBLK) * 256 + threadIdx.x;
        if (e >= E) return;
        const int s = src[e];
        const int d = dest[e];
        const float dx = R[3 * s + 0] - R[3 * d + 0];
        const float dy = R[3 * s + 1] - R[3 * d + 1];
        const float dz = R[3 * s + 2] - R[3 * d + 2];
        const float D2 = fmaf(dx, dx, fmaf(dy, dy, dz * dz));
        const float u = fminf(D2 * TINV, (float)TG);
        const int pos = atomicAdd(&cursor[d], 1);
        ep[pos] = make_float2(__int_as_float(s), u);
    }
}

// ---------------------------------------------------------------------------
// K4: gather-accumulate. One wave per dest node (50K waves), 4-edge unroll,
// two independent accumulator chains. ep streamed nontemporally; X/Tp cached.
// ---------------------------------------------------------------------------
__global__ __launch_bounds__(256) void gather_accum(
    const int* __restrict__ starts, const float2* __restrict__ ep,
    const float2* __restrict__ X2, const float4* __restrict__ Tp4,
    float* __restrict__ H, int V) {
    const int node = blockIdx.x * 4 + (threadIdx.x >> 6);
    const int lane = threadIdx.x & 63;
    if (node >= V) return;
    int i = starts[node];
    const int end = starts[node + 1];
    float a0x = 0.f, a0y = 0.f, a1x = 0.f, a1y = 0.f;
    for (; i + 4 <= end; i += 4) {
        const f2v e0 = __builtin_nontemporal_load((const f2v*)(ep + i));
        const f2v e1 = __builtin_nontemporal_load((const f2v*)(ep + i + 1));
        const f2v e2 = __builtin_nontemporal_load((const f2v*)(ep + i + 2));
        const f2v e3 = __builtin_nontemporal_load((const f2v*)(ep + i + 3));
        const int s0 = __float_as_int(e0.x);
        const int s1 = __float_as_int(e1.x);
        const int s2 = __float_as_int(e2.x);
        const int s3 = __float_as_int(e3.x);
        int g0 = (int)e0.y; if (g0 > TG - 1) g0 = TG - 1;
        int g1 = (int)e1.y; if (g1 > TG - 1) g1 = TG - 1;
        int g2 = (int)e2.y; if (g2 > TG - 1) g2 = TG - 1;
        int g3 = (int)e3.y; if (g3 > TG - 1) g3 = TG - 1;
        const float t0 = e0.y - (float)g0;
        const float t1 = e1.y - (float)g1;
        const float t2 = e2.y - (float)g2;
        const float t3 = e3.y - (float)g3;
        const float4 q0 = Tp4[(size_t)g0 * 64 + lane];
        const float4 q1 = Tp4[(size_t)g1 * 64 + lane];
        const float4 q2 = Tp4[(size_t)g2 * 64 + lane];
        const float4 q3 = Tp4[(size_t)g3 * 64 + lane];
        const float2 x0 = X2[(size_t)s0 * 64 + lane];
        const float2 x1 = X2[(size_t)s1 * 64 + lane];
        const float2 x2 = X2[(size_t)s2 * 64 + lane];
        const float2 x3 = X2[(size_t)s3 * 64 + lane];
        a0x = fmaf(fmaf(t0, q0.y - q0.x, q0.x), x0.x, a0x);
        a0y = fmaf(fmaf(t0, q0.w - q0.z, q0.z), x0.y, a0y);
        a1x = fmaf(fmaf(t1, q1.y - q1.x, q1.x), x1.x, a1x);
        a1y = fmaf(fmaf(t1, q1.w - q1.z, q1.z), x1.y, a1y);
        a0x = fmaf(fmaf(t2, q2.y - q2.x, q2.x), x2.x, a0x);
        a0y = fmaf(fmaf(t2, q2.w - q2.z, q2.z), x2.y, a0y);
        a1x = fmaf(fmaf(t3, q3.y - q3.x, q3.x), x3.x, a1x);
        a1y = fmaf(fmaf(t3, q3.w - q3.z, q3.z), x3.y, a1y);
    }
    for (; i < end; ++i) {
        const f2v e0 = __builtin_nontemporal_load((const f2v*)(ep + i));
        const int s0 = __float_as_int(e0.x);
        int g0 = (int)e0.y; if (g0 > TG - 1) g0 = TG - 1;
        const float t0 = e0.y - (float)g0;
        const float4 q0 = Tp4[(size_t)g0 * 64 + lane];
        const float2 x0 = X2[(size_t)s0 * 64 + lane];
        a0x = fmaf(fmaf(t0, q0.y - q0.x, q0.x), x0.x, a0x);
        a0y = fmaf(fmaf(t0, q0.w - q0.z, q0.z), x0.y, a0y);
    }
    ((float2*)H)[(size_t)node * 64 + lane] = make_float2(a0x + a1x, a0y + a1y);
}

// ---------------------------------------------------------------------------
// K5: fused node MLP: out = relu(H@U1 + b1)@U2 + b2.
// ---------------------------------------------------------------------------
#define NROWS 32
#define RPW 8

__global__ __launch_bounds__(256) void node_mlp(
    const float* __restrict__ H, const float* __restrict__ U1,
    const float* __restrict__ b1, const float* __restrict__ U2,
    const float* __restrict__ b2, float* __restrict__ out, int V) {
    __shared__ float hs[NROWS * HIDDEN];
    __shared__ float ts[NROWS * HIDDEN];
    const int tid = threadIdx.x;
    const int lane = tid & 63;
    const int wave = tid >> 6;
    const int r0 = blockIdx.x * NROWS;

    const float4* Hg4 = (const float4*)(H + (size_t)r0 * HIDDEN);
    float4* hs4 = (float4*)hs;
    const long long max4 = (long long)(V - r0) * (HIDDEN / 4);
#pragma unroll
    for (int i = 0; i < 4; ++i) {
        const int idx = tid + i * 256;
        float4 v = make_float4(0.f, 0.f, 0.f, 0.f);
        if (idx < max4) v = Hg4[idx];
        hs4[idx] = v;
    }
    __syncthreads();

    const float2* U1g = (const float2*)U1;
    const float2* U2g = (const float2*)U2;
    const float2 bb1 = ((const float2*)b1)[lane];
    const float2 bb2 = ((const float2*)b2)[lane];
    const int lr0 = wave * RPW;

    float2 acc[RPW];
#pragma unroll
    for (int j = 0; j < RPW; ++j) acc[j] = bb1;
    for (int k4 = 0; k4 < HIDDEN / 4; ++k4) {
        const float2 u0 = U1g[(k4 * 4 + 0) * 64 + lane];
        const float2 u1 = U1g[(k4 * 4 + 1) * 64 + lane];
        const float2 u2 = U1g[(k4 * 4 + 2) * 64 + lane];
        const float2 u3 = U1g[(k4 * 4 + 3) * 64 + lane];
#pragma unroll
        for (int j = 0; j < RPW; ++j) {
            const float4 h4 = *(const float4*)&hs[(lr0 + j) * HIDDEN + k4 * 4];
            acc[j].x = fmaf(h4.x, u0.x, acc[j].x);
            acc[j].y = fmaf(h4.x, u0.y, acc[j].y);
            acc[j].x = fmaf(h4.y, u1.x, acc[j].x);
            acc[j].y = fmaf(h4.y, u1.y, acc[j].y);
            acc[j].x = fmaf(h4.z, u2.x, acc[j].x);
            acc[j].y = fmaf(h4.z, u2.y, acc[j].y);
            acc[j].x = fmaf(h4.w, u3.x, acc[j].x);
            acc[j].y = fmaf(h4.w, u3.y, acc[j].y);
        }
    }
#pragma unroll
    for (int j = 0; j < RPW; ++j) {
        float2 t;
        t.x = fmaxf(acc[j].x, 0.0f);
        t.y = fmaxf(acc[j].y, 0.0f);
        *(float2*)&ts[(lr0 + j) * HIDDEN + 2 * lane] = t;
    }
    __syncthreads();

#pragma unroll
    for (int j = 0; j < RPW; ++j) acc[j] = bb2;
    for (int k4 = 0; k4 < HIDDEN / 4; ++k4) {
        const float2 u0 = U2g[(k4 * 4 + 0) * 64 + lane];
        const float2 u1 = U2g[(k4 * 4 + 1) * 64 + lane];
        const float2 u2 = U2g[(k4 * 4 + 2) * 64 + lane];
        const float2 u3 = U2g[(k4 * 4 + 3) * 64 + lane];
#pragma unroll
        for (int j = 0; j < RPW; ++j) {
            const float4 h4 = *(const float4*)&ts[(lr0 + j) * HIDDEN + k4 * 4];
            acc[j].x = fmaf(h4.x, u0.x, acc[j].x);
            acc[j].y = fmaf(h4.x, u0.y, acc[j].y);
            acc[j].x = fmaf(h4.y, u1.x, acc[j].x);
            acc[j].y = fmaf(h4.y, u1.y, acc[j].y);
            acc[j].x = fmaf(h4.z, u2.x, acc[j].x);
            acc[j].y = fmaf(h4.z, u2.y, acc[j].y);
            acc[j].x = fmaf(h4.w, u3.x, acc[j].x);
            acc[j].y = fmaf(h4.w, u3.y, acc[j].y);
        }
    }
    float2* out2 = (float2*)out;
#pragma unroll
    for (int j = 0; j < RPW; ++j) {
        const int row = r0 + lr0 + j;
        if (row < V) out2[(size_t)row * 64 + lane] = acc[j];
    }
}

// ---------------------------------------------------------------------------
extern "C" void kernel_launch(void* const* d_in, const int* in_sizes, int n_in,
                              void* d_out, int out_size, void* d_ws, size_t ws_size,
                              hipStream_t stream) {
    const float* X = (const float*)d_in[0];
    const float* R = (const float*)d_in[1];
    const int* src = (const int*)d_in[2];
    const int* dest = (const int*)d_in[3];
    const float* W1 = (const float*)d_in[4];
    const float* W2 = (const float*)d_in[5];
    const float* U1 = (const float*)d_in[6];
    const float* b1 = (const float*)d_in[7];
    const float* U2 = (const float*)d_in[8];
    const float* b2 = (const float*)d_in[9];

    const int V = in_sizes[0] / HIDDEN;
    const int E = in_sizes[2];
    const int EB = (E + 255) / 256;

    // workspace layout (16B-aligned sections)
    char* base = (char*)d_ws;
    float* Hbuf = (float*)base;                 base += (size_t)V * HIDDEN * sizeof(float);
    float2* Tp = (float2*)base;                 base += (size_t)TG * HIDDEN * sizeof(float2);
    float2* ep = (float2*)base;                 base += (size_t)E * sizeof(float2);
    int* cnt = (int*)base;                      base += (size_t)VPAD * sizeof(int);
    int* starts = (int*)base;                   base += (size_t)VPAD * sizeof(int);
    int* cursor = (int*)base;                   base += (size_t)VPAD * sizeof(int);
    float* W1T = (float*)base;                  base += (size_t)NB * HIDDEN * sizeof(float);
    float* W2T = (float*)base;

    hipMemsetAsync(cnt, 0, (size_t)VPAD * sizeof(int), stream);
    prep_hist<<<64 + EB, 256, 0, stream>>>(W1, W2, W1T, W2T, dest, cnt, E);
    scan_counts<<<1, 1024, 0, stream>>>(cnt, starts, cursor);
    table_scatter<<<NTBLK + EB, 256, 0, stream>>>(W1T, W2T, Tp, src, dest, R,
                                                  cursor, ep, E);
    gather_accum<<<(V + 3) / 4, 256, 0, stream>>>(starts, ep, (const float2*)X,
                                                  (const float4*)Tp, Hbuf, V);
    node_mlp<<<(V + NROWS - 1) / NROWS, 256, 0, stream>>>(Hbuf, U1, b1, U2, b2,
                                                          (float*)d_out, V);
}